// Round 13
// baseline (169.796 us; speedup 1.0000x reference)
//
#include <hip/hip_runtime.h>
#include <math.h>

#define NROWS 32768
#define DDIM 256
#define KCODES 1024
#define KSPLIT 8

typedef __attribute__((ext_vector_type(8))) short bf16x8;
typedef __attribute__((ext_vector_type(4))) float f32x4;
typedef __attribute__((ext_vector_type(4))) unsigned short u16x4;

__device__ __forceinline__ unsigned short f2bf(float f) {
    unsigned int u;
    __builtin_memcpy(&u, &f, 4);
    u += 0x7fffu + ((u >> 16) & 1u);
    return (unsigned short)(u >> 16);
}

// margin >= 2*eps_screen. Rigorous: 2eps <= 2^-7 * ||e||max * sqrt(x2),
// ||e|| <= 0.8  ->  0.00625*sqrt(x2). We use 2.2x that.
__device__ __forceinline__ float screen_margin(float x2v) {
    return 0.014f * sqrtf(x2v) + 5e-4f;
}

// ---- x2 = np.sum(x*x,1) via numpy AVX512 pairwise tree (bit-exact, R6) -----
constexpr int X2ROWS = 32;
__global__ __launch_bounds__(256) void vq_x2xb(const float* __restrict__ x,
                                               float* __restrict__ x2,
                                               unsigned short* __restrict__ xb) {
    __shared__ float lds[X2ROWS][257];
    const int rb = blockIdx.x;
    const int tid = threadIdx.x;
    const float4* src =
        reinterpret_cast<const float4*>(x + (size_t)rb * X2ROWS * DDIM);
#pragma unroll
    for (int i = 0; i < 8; ++i) {
        int e4 = tid + i * 256;
        int row = e4 >> 6;
        int col = e4 & 63;
        float4 v = src[e4];
        lds[row][col * 4 + 0] = v.x;
        lds[row][col * 4 + 1] = v.y;
        lds[row][col * 4 + 2] = v.z;
        lds[row][col * 4 + 3] = v.w;
        u16x4 h;
        h.x = f2bf(v.x);
        h.y = f2bf(v.y);
        h.z = f2bf(v.z);
        h.w = f2bf(v.w);
        *reinterpret_cast<u16x4*>(&xb[(size_t)rb * X2ROWS * DDIM + e4 * 4]) = h;
    }
    __syncthreads();
    if (tid < X2ROWS) {
        const float* r = lds[tid];
        float halves[2];
#pragma unroll
        for (int h = 0; h < 2; ++h) {
            const float* b = r + h * 128;
            float L[16];
#pragma unroll
            for (int p = 0; p < 16; ++p) {
                float t0 = __fmul_rn(b[p], b[p]);
                float t1 = __fmul_rn(b[16 + p], b[16 + p]);
                float t2 = __fmul_rn(b[32 + p], b[32 + p]);
                float t3 = __fmul_rn(b[48 + p], b[48 + p]);
                float t4 = __fmul_rn(b[64 + p], b[64 + p]);
                float t5 = __fmul_rn(b[80 + p], b[80 + p]);
                float t6 = __fmul_rn(b[96 + p], b[96 + p]);
                float t7 = __fmul_rn(b[112 + p], b[112 + p]);
                L[p] = __fadd_rn(
                    __fadd_rn(__fadd_rn(t0, t1), __fadd_rn(t2, t3)),
                    __fadd_rn(__fadd_rn(t4, t5), __fadd_rn(t6, t7)));
            }
            float s1[8];
#pragma unroll
            for (int p = 0; p < 8; ++p) s1[p] = __fadd_rn(L[p], L[p + 8]);
            float s2[4];
#pragma unroll
            for (int p = 0; p < 4; ++p) s2[p] = __fadd_rn(s1[p], s1[p + 4]);
            float s30 = __fadd_rn(s2[0], s2[2]);
            float s31 = __fadd_rn(s2[1], s2[3]);
            halves[h] = __fadd_rn(s30, s31);
        }
        x2[(size_t)rb * X2ROWS + tid] = __fadd_rn(halves[0], halves[1]);
    }
}

// ---- e2[k]: sequential axis-0 sum (bit-exact, R6) --------------------------
__global__ __launch_bounds__(256) void vq_e2(const float* __restrict__ e,
                                             float* __restrict__ e2) {
    int k = blockIdx.x * 256 + threadIdx.x;
    float v0 = e[k];
    float s = __fmul_rn(v0, v0);
    for (int d = 1; d < DDIM; ++d) {
        float v = e[d * KCODES + k];
        s = __fadd_rn(s, __fmul_rn(v, v));
    }
    e2[k] = s;
}

// ---- transpose E -> ET f32 + ETb bf16 --------------------------------------
__global__ __launch_bounds__(256) void vq_transpose(
    const float* __restrict__ e, float* __restrict__ et,
    unsigned short* __restrict__ etb) {
    __shared__ float tile[32][33];
    int bk = blockIdx.x;
    int bd = blockIdx.y;
    int tx = threadIdx.x & 31;
    int ty = threadIdx.x >> 5;
#pragma unroll
    for (int p = 0; p < 4; ++p)
        tile[ty + p * 8][tx] = e[(bd * 32 + ty + p * 8) * KCODES + bk * 32 + tx];
    __syncthreads();
#pragma unroll
    for (int p = 0; p < 4; ++p) {
        float v = tile[tx][ty + p * 8];
        size_t o = (size_t)(bk * 32 + ty + p * 8) * DDIM + bd * 32 + tx;
        et[o] = v;
        etb[o] = f2bf(v);
    }
}

// ---- screen: bf16 MFMA + per-block top-2/argmin + masks --------------------
constexpr int ASTR = 40;
__global__ __launch_bounds__(256) void vq_screen(
    const unsigned short* __restrict__ xb, const unsigned short* __restrict__ etb,
    const float* __restrict__ e2g, const float* __restrict__ x2g,
    unsigned int* __restrict__ masks, float* __restrict__ pdist1,
    int* __restrict__ pidx1, float* __restrict__ pdist2) {
    __shared__ __align__(16) unsigned short Ab[128 * ASTR];
    __shared__ __align__(16) unsigned short Bb[128 * ASTR];
    __shared__ float e2s[128];
    __shared__ float s1l[2][128];
    __shared__ int sil[2][128];
    __shared__ float s2l[2][128];
    __shared__ unsigned int mlds[128][4];

    const int rb = blockIdx.x;
    const int ks = blockIdx.y;
    const int row0 = rb * 128;
    const int c0 = ks * 128;
    const int tid = threadIdx.x;
    const int w = tid >> 6;
    const int lane = tid & 63;
    const int wr = w >> 1, wc = w & 1;
    const int l15 = lane & 15, l4 = lane >> 4;

    if (tid < 128) e2s[tid] = e2g[c0 + tid];
    for (int q = tid; q < 512; q += 256)
        reinterpret_cast<unsigned int*>(mlds)[q] = 0u;

    f32x4 acc[4][4];
#pragma unroll
    for (int i = 0; i < 4; ++i)
#pragma unroll
        for (int j = 0; j < 4; ++j) acc[i][j] = (f32x4)(0.f);

    for (int d0 = 0; d0 < DDIM; d0 += 32) {
#pragma unroll
        for (int p = 0; p < 2; ++p) {
            int L = tid + p * 256;
            int r = L >> 2, g = L & 3;
            const uint4 va = *reinterpret_cast<const uint4*>(
                &xb[(size_t)(row0 + r) * DDIM + d0 + g * 8]);
            *reinterpret_cast<uint4*>(&Ab[r * ASTR + g * 8]) = va;
            const uint4 vb = *reinterpret_cast<const uint4*>(
                &etb[(size_t)(c0 + r) * DDIM + d0 + g * 8]);
            *reinterpret_cast<uint4*>(&Bb[r * ASTR + g * 8]) = vb;
        }
        __syncthreads();
        bf16x8 bfr[4];
#pragma unroll
        for (int j = 0; j < 4; ++j)
            bfr[j] = *reinterpret_cast<const bf16x8*>(
                &Bb[(wc * 64 + j * 16 + l15) * ASTR + l4 * 8]);
#pragma unroll
        for (int i = 0; i < 4; ++i) {
            bf16x8 af = *reinterpret_cast<const bf16x8*>(
                &Ab[(wr * 64 + i * 16 + l15) * ASTR + l4 * 8]);
#pragma unroll
            for (int j = 0; j < 4; ++j)
                acc[i][j] = __builtin_amdgcn_mfma_f32_16x16x32_bf16(
                    af, bfr[j], acc[i][j], 0, 0, 0);
        }
        __syncthreads();
    }

    // top-2 + argmin per (wc half, row): sequential (i,reg), low reg pressure
#pragma unroll
    for (int i = 0; i < 4; ++i) {
#pragma unroll
        for (int reg = 0; reg < 4; ++reg) {
            float b1 = INFINITY, b2 = INFINITY;
            int i1 = 0x7fffffff;
#pragma unroll
            for (int j = 0; j < 4; ++j) {
                int cl = wc * 64 + j * 16 + l15;
                float d = e2s[cl] - 2.f * acc[i][j][reg];
                if (d < b1) {
                    b2 = b1;
                    b1 = d;
                    i1 = cl;
                } else {
                    b2 = fminf(b2, d);
                }
            }
#pragma unroll
            for (int m = 1; m < 16; m <<= 1) {
                float od1 = __shfl_xor(b1, m);
                int oi1 = __shfl_xor(i1, m);
                float od2 = __shfl_xor(b2, m);
                if (od1 < b1 || (od1 == b1 && oi1 < i1)) {
                    b2 = fminf(b1, od2);
                    b1 = od1;
                    i1 = oi1;
                } else {
                    b2 = fminf(b2, od1);
                }
            }
            if (l15 == 0) {
                int rl = wr * 64 + i * 16 + l4 * 4 + reg;
                s1l[wc][rl] = b1;
                sil[wc][rl] = i1;
                s2l[wc][rl] = b2;
            }
        }
    }
    __syncthreads();

    // merge halves, write per-(row, ks) triples
    if (tid < 128) {
        float g1 = s1l[0][tid], g2 = s2l[0][tid];
        int gi = sil[0][tid];
        float ob = s1l[1][tid];
        if (ob < g1) {
            g2 = fminf(g1, s2l[1][tid]);
            g1 = ob;
            gi = sil[1][tid];
        } else {
            g2 = fminf(g2, ob);
        }
        pdist1[(size_t)ks * NROWS + row0 + tid] = g1;
        pidx1[(size_t)ks * NROWS + row0 + tid] = c0 + gi;
        pdist2[(size_t)ks * NROWS + row0 + tid] = g2;
    }

    // candidate masks (thr = block-min + margin)
#pragma unroll
    for (int i = 0; i < 4; ++i)
#pragma unroll
        for (int reg = 0; reg < 4; ++reg) {
            int rl = wr * 64 + i * 16 + l4 * 4 + reg;
            float g1row = fminf(s1l[0][rl], s1l[1][rl]);
            float thr = g1row + screen_margin(x2g[row0 + rl]);
#pragma unroll
            for (int j = 0; j < 4; ++j) {
                int cl = wc * 64 + j * 16 + l15;
                float d = e2s[cl] - 2.f * acc[i][j][reg];
                if (d <= thr)
                    atomicOr(&mlds[rl][cl >> 5], 1u << (cl & 31));
            }
        }
    __syncthreads();
    for (int q = tid; q < 512; q += 256) {
        int r = q >> 2, wq = q & 3;
        masks[(size_t)(row0 + r) * 32 + ks * 4 + wq] = mlds[r][wq];
    }
}

// ---- pick: resolve wide-gap rows directly; flag near-ties ------------------
__global__ __launch_bounds__(256) void vq_pick(
    const float* __restrict__ pdist1, const int* __restrict__ pidx1,
    const float* __restrict__ pdist2, const float* __restrict__ x2g,
    int* __restrict__ idx, int* __restrict__ flag) {
    int row = blockIdx.x * 256 + threadIdx.x;
    float g1 = INFINITY, g2 = INFINITY;
    int gi = 0;
#pragma unroll
    for (int s = 0; s < KSPLIT; ++s) {
        float d1 = pdist1[(size_t)s * NROWS + row];
        int i1 = pidx1[(size_t)s * NROWS + row];
        float d2 = pdist2[(size_t)s * NROWS + row];
        if (d1 < g1) {
            g2 = fminf(g1, d2);
            g1 = d1;
            gi = i1;
        } else {
            g2 = fminf(g2, d1);
        }
    }
    // gap > margin >= 2*eps  ==>  gi is the unique np argmin
    if (g2 - g1 > screen_margin(x2g[row])) {
        idx[row] = gi & (KCODES - 1);
        flag[row] = 0;
    } else {
        flag[row] = 1;
    }
}

// ---- rescan (flag-gated): block pruning + parallel extract + np-exact dot --
__global__ __launch_bounds__(64) void vq_rescan(
    const float* __restrict__ x, const float* __restrict__ et,
    const float* __restrict__ x2g, const float* __restrict__ e2g,
    const unsigned int* __restrict__ masks, const float* __restrict__ pdist1,
    const int* __restrict__ flag, int* __restrict__ idx) {
    const int lane = threadIdx.x;
    const int row = blockIdx.x;
    if (flag[row] == 0) return;

    __shared__ float xrow[256];
    __shared__ int cand[64];
    __shared__ float bmins[8];

    if (lane < 8) bmins[lane] = pdist1[(size_t)lane * NROWS + row];
    __syncthreads();
    float gmin = fminf(fminf(fminf(bmins[0], bmins[1]), fminf(bmins[2], bmins[3])),
                       fminf(fminf(bmins[4], bmins[5]), fminf(bmins[6], bmins[7])));
    const float x2r = x2g[row];
    const float margin = screen_margin(x2r);

    unsigned int wmask = 0u;
    if (lane < 32) {
        if (bmins[lane >> 2] <= gmin + margin)
            wmask = masks[(size_t)row * 32 + lane];
    }
    int mycnt = __popc(wmask);
    int pre = mycnt;
#pragma unroll
    for (int off = 1; off < 32; off <<= 1) {
        int t = __shfl_up(pre, off);
        if (lane >= off) pre += t;
    }
    const int total = __shfl(pre, 31);
    if (lane < 32) {
        int off = pre - mycnt;
        unsigned int b = wmask;
        while (b) {
            int t = __ffs(b) - 1;
            if (off < 64) cand[off] = lane * 32 + t;
            ++off;
            b &= b - 1;
        }
    }
    __syncthreads();

    if (total == 1) {
        if (lane == 0) idx[row] = cand[0] & (KCODES - 1);
    } else {
        *reinterpret_cast<float4*>(&xrow[lane * 4]) =
            *reinterpret_cast<const float4*>(&x[(size_t)row * DDIM + lane * 4]);
        __syncthreads();

        float best = INFINITY;
        int bk = 0x7fffffff;
        if (total <= 64) {
            if (lane < total) {
                int k = cand[lane];
                const float4* er =
                    reinterpret_cast<const float4*>(&et[(size_t)k * DDIM]);
                const float4* xr4 = reinterpret_cast<const float4*>(xrow);
                float s = 0.f;
#pragma unroll 4
                for (int g = 0; g < 64; ++g) {  // in-order d chain (np-exact)
                    float4 ev = er[g];
                    float4 xv = xr4[g];
                    s = fmaf(xv.x, ev.x, s);
                    s = fmaf(xv.y, ev.y, s);
                    s = fmaf(xv.z, ev.z, s);
                    s = fmaf(xv.w, ev.w, s);
                }
                float u = __fadd_rn(x2r, e2g[k]);
                best = __fsub_rn(u, __fmul_rn(2.0f, s));
                bk = k;
            }
        } else {
#pragma unroll 1
            for (int c = 0; c < 16; ++c) {
                int k = lane + c * 64;
                const float4* er =
                    reinterpret_cast<const float4*>(&et[(size_t)k * DDIM]);
                const float4* xr4 = reinterpret_cast<const float4*>(xrow);
                float s = 0.f;
#pragma unroll 4
                for (int g = 0; g < 64; ++g) {
                    float4 ev = er[g];
                    float4 xv = xr4[g];
                    s = fmaf(xv.x, ev.x, s);
                    s = fmaf(xv.y, ev.y, s);
                    s = fmaf(xv.z, ev.z, s);
                    s = fmaf(xv.w, ev.w, s);
                }
                float u = __fadd_rn(x2r, e2g[k]);
                float dct = __fsub_rn(u, __fmul_rn(2.0f, s));
                if (dct < best || (dct == best && k < bk)) {
                    best = dct;
                    bk = k;
                }
            }
        }
#pragma unroll
        for (int m = 1; m < 64; m <<= 1) {
            float od = __shfl_xor(best, m);
            int oi = __shfl_xor(bk, m);
            if (od < best || (od == best && oi < bk)) {
                best = od;
                bk = oi;
            }
        }
        if (lane == 0) idx[row] = bk & (KCODES - 1);
    }
}

// ---- output: gather + fp32 STE out + loss partial (verified) ---------------
__global__ __launch_bounds__(256) void vq_output(
    const float* __restrict__ x, const float* __restrict__ et,
    const int* __restrict__ idx, float* __restrict__ out,
    float* __restrict__ blockloss) {
    __shared__ int skb[64];
    __shared__ float red[256];
    const int rb = blockIdx.x;
    const int tid = threadIdx.x;
    if (tid < 64) skb[tid] = idx[rb * 64 + tid];
    __syncthreads();
    float lsum = 0.f;
    for (int r = 0; r < 64; ++r) {
        int row = rb * 64 + r;
        int k = skb[r];
        float xv = x[(size_t)row * DDIM + tid];
        float qv = et[(size_t)k * DDIM + tid];
        float diff = __fsub_rn(qv, xv);
        float qst = __fadd_rn(xv, diff);
        out[(size_t)row * DDIM + tid] = qst;
        lsum = fmaf(diff, diff, lsum);
    }
    red[tid] = lsum;
    __syncthreads();
    for (int s = 128; s > 0; s >>= 1) {
        if (tid < s) red[tid] += red[tid + s];
        __syncthreads();
    }
    if (tid == 0) blockloss[rb] = red[0];
}

// ---- deterministic loss reduce (verified) ----------------------------------
__global__ __launch_bounds__(512) void vq_loss_reduce(
    const float* __restrict__ blockloss, float* __restrict__ out_loss) {
    __shared__ float red[512];
    int tid = threadIdx.x;
    red[tid] = blockloss[tid];
    __syncthreads();
    for (int s = 256; s > 0; s >>= 1) {
        if (tid < s) red[tid] += red[tid + s];
        __syncthreads();
    }
    if (tid == 0) {
        float m = __fmul_rn(red[0], 1.0f / (float)((size_t)NROWS * DDIM));
        out_loss[0] = __fadd_rn(__fmul_rn(0.25f, m), m);
    }
}

extern "C" void kernel_launch(void* const* d_in, const int* in_sizes, int n_in,
                              void* d_out, int out_size, void* d_ws,
                              size_t ws_size, hipStream_t stream) {
    const float* x = (const float*)d_in[0];  // [32768, 256] fp32
    const float* e = (const float*)d_in[1];  // [256, 1024]  fp32
    float* out = (float*)d_out;              // 8388608 qst + 1 loss, fp32

    float* ws = (float*)d_ws;
    float* x2 = ws;                                    // 32768
    float* e2 = x2 + NROWS;                            // 1024
    float* et = e2 + KCODES;                           // 262144
    unsigned short* etb = (unsigned short*)(et + (size_t)KCODES * DDIM);
    unsigned short* xb = etb + (size_t)KCODES * DDIM;  // 8388608 u16
    unsigned int* masks = (unsigned int*)(xb + (size_t)NROWS * DDIM);
    float* pdist1 = (float*)(masks + (size_t)NROWS * 32);   // 8*32768
    int* pidx1 = (int*)(pdist1 + (size_t)KSPLIT * NROWS);   // 8*32768
    float* pdist2 = (float*)(pidx1 + (size_t)KSPLIT * NROWS);
    int* idx = (int*)(pdist2 + (size_t)KSPLIT * NROWS);     // 32768
    int* flag = idx + NROWS;                                // 32768
    float* blockloss = (float*)(flag + NROWS);              // 512

    vq_x2xb<<<NROWS / X2ROWS, 256, 0, stream>>>(x, x2, xb);
    vq_e2<<<KCODES / 256, 256, 0, stream>>>(e, e2);
    vq_transpose<<<dim3(32, 8), 256, 0, stream>>>(e, et, etb);
    vq_screen<<<dim3(NROWS / 128, KCODES / 128), 256, 0, stream>>>(
        xb, etb, e2, x2, masks, pdist1, pidx1, pdist2);
    vq_pick<<<NROWS / 256, 256, 0, stream>>>(pdist1, pidx1, pdist2, x2, idx,
                                             flag);
    vq_rescan<<<NROWS, 64, 0, stream>>>(x, et, x2, e2, masks, pdist1, flag, idx);
    vq_output<<<NROWS / 64, 256, 0, stream>>>(x, et, idx, out, blockloss);
    vq_loss_reduce<<<1, 512, 0, stream>>>(blockloss, out + (size_t)NROWS * DDIM);
}

// Round 14
// 140.385 us; speedup vs baseline: 1.2095x; 1.2095x over previous
//
#include <hip/hip_runtime.h>
#include <math.h>

#define NROWS 32768
#define DDIM 256
#define KCODES 1024

typedef __attribute__((ext_vector_type(8))) short bf16x8;
typedef __attribute__((ext_vector_type(4))) float f32x4;
typedef __attribute__((ext_vector_type(4))) unsigned short u16x4;

__device__ __forceinline__ unsigned short f2bf(float f) {
    unsigned int u;
    __builtin_memcpy(&u, &f, 4);
    u += 0x7fffu + ((u >> 16) & 1u);
    return (unsigned short)(u >> 16);
}

// margin >= 2*eps_screen. Rigorous: 2eps <= 2^-7 * ||e||max * sqrt(x2),
// ||e|| <= 0.8  ->  0.00625*sqrt(x2). We use 2.24x that. (field-tested R13)
__device__ __forceinline__ float screen_margin(float x2v) {
    return 0.014f * sqrtf(x2v) + 5e-4f;
}

// ---- x2 = np.sum(x*x,1) via numpy AVX512 pairwise tree (bit-exact, R6) -----
constexpr int X2ROWS = 32;
__global__ __launch_bounds__(256) void vq_x2xb(const float* __restrict__ x,
                                               float* __restrict__ x2,
                                               unsigned short* __restrict__ xb) {
    __shared__ float lds[X2ROWS][257];
    const int rb = blockIdx.x;
    const int tid = threadIdx.x;
    const float4* src =
        reinterpret_cast<const float4*>(x + (size_t)rb * X2ROWS * DDIM);
#pragma unroll
    for (int i = 0; i < 8; ++i) {
        int e4 = tid + i * 256;
        int row = e4 >> 6;
        int col = e4 & 63;
        float4 v = src[e4];
        lds[row][col * 4 + 0] = v.x;
        lds[row][col * 4 + 1] = v.y;
        lds[row][col * 4 + 2] = v.z;
        lds[row][col * 4 + 3] = v.w;
        u16x4 h;
        h.x = f2bf(v.x);
        h.y = f2bf(v.y);
        h.z = f2bf(v.z);
        h.w = f2bf(v.w);
        *reinterpret_cast<u16x4*>(&xb[(size_t)rb * X2ROWS * DDIM + e4 * 4]) = h;
    }
    __syncthreads();
    if (tid < X2ROWS) {
        const float* r = lds[tid];
        float halves[2];
#pragma unroll
        for (int h = 0; h < 2; ++h) {
            const float* b = r + h * 128;
            float L[16];
#pragma unroll
            for (int p = 0; p < 16; ++p) {
                float t0 = __fmul_rn(b[p], b[p]);
                float t1 = __fmul_rn(b[16 + p], b[16 + p]);
                float t2 = __fmul_rn(b[32 + p], b[32 + p]);
                float t3 = __fmul_rn(b[48 + p], b[48 + p]);
                float t4 = __fmul_rn(b[64 + p], b[64 + p]);
                float t5 = __fmul_rn(b[80 + p], b[80 + p]);
                float t6 = __fmul_rn(b[96 + p], b[96 + p]);
                float t7 = __fmul_rn(b[112 + p], b[112 + p]);
                L[p] = __fadd_rn(
                    __fadd_rn(__fadd_rn(t0, t1), __fadd_rn(t2, t3)),
                    __fadd_rn(__fadd_rn(t4, t5), __fadd_rn(t6, t7)));
            }
            float s1[8];
#pragma unroll
            for (int p = 0; p < 8; ++p) s1[p] = __fadd_rn(L[p], L[p + 8]);
            float s2[4];
#pragma unroll
            for (int p = 0; p < 4; ++p) s2[p] = __fadd_rn(s1[p], s1[p + 4]);
            float s30 = __fadd_rn(s2[0], s2[2]);
            float s31 = __fadd_rn(s2[1], s2[3]);
            halves[h] = __fadd_rn(s30, s31);
        }
        x2[(size_t)rb * X2ROWS + tid] = __fadd_rn(halves[0], halves[1]);
    }
}

// ---- e2[k]: sequential axis-0 sum (bit-exact, R6) --------------------------
__global__ __launch_bounds__(256) void vq_e2(const float* __restrict__ e,
                                             float* __restrict__ e2) {
    int k = blockIdx.x * 256 + threadIdx.x;
    float v0 = e[k];
    float s = __fmul_rn(v0, v0);
    for (int d = 1; d < DDIM; ++d) {
        float v = e[d * KCODES + k];
        s = __fadd_rn(s, __fmul_rn(v, v));
    }
    e2[k] = s;
}

// ---- transpose E -> ET f32 + ETb bf16 --------------------------------------
__global__ __launch_bounds__(256) void vq_transpose(
    const float* __restrict__ e, float* __restrict__ et,
    unsigned short* __restrict__ etb) {
    __shared__ float tile[32][33];
    int bk = blockIdx.x;
    int bd = blockIdx.y;
    int tx = threadIdx.x & 31;
    int ty = threadIdx.x >> 5;
#pragma unroll
    for (int p = 0; p < 4; ++p)
        tile[ty + p * 8][tx] = e[(bd * 32 + ty + p * 8) * KCODES + bk * 32 + tx];
    __syncthreads();
#pragma unroll
    for (int p = 0; p < 4; ++p) {
        float v = tile[tx][ty + p * 8];
        size_t o = (size_t)(bk * 32 + ty + p * 8) * DDIM + bd * 32 + tx;
        et[o] = v;
        etb[o] = f2bf(v);
    }
}

// ---- screen: bf16 MFMA GEMM 128x128 + masks + block mins (R12 structure) ---
constexpr int ASTR = 40;
__global__ __launch_bounds__(256) void vq_screen(
    const unsigned short* __restrict__ xb, const unsigned short* __restrict__ etb,
    const float* __restrict__ e2g, const float* __restrict__ x2g,
    unsigned int* __restrict__ masks, float* __restrict__ bmin) {
    __shared__ __align__(16) unsigned short Ab[128 * ASTR];
    __shared__ __align__(16) unsigned short Bb[128 * ASTR];
    __shared__ float rowmin2[2][128];
    __shared__ unsigned int mlds[128][4];

    const int rb = blockIdx.x;
    const int ks = blockIdx.y;
    const int row0 = rb * 128;
    const int c0 = ks * 128;
    const int tid = threadIdx.x;
    const int w = tid >> 6;
    const int lane = tid & 63;
    const int wr = w >> 1, wc = w & 1;
    const int l15 = lane & 15, l4 = lane >> 4;

    for (int q = tid; q < 512; q += 256)
        reinterpret_cast<unsigned int*>(mlds)[q] = 0u;

    f32x4 acc[4][4];
#pragma unroll
    for (int i = 0; i < 4; ++i)
#pragma unroll
        for (int j = 0; j < 4; ++j) acc[i][j] = (f32x4)(0.f);

    for (int d0 = 0; d0 < DDIM; d0 += 32) {
#pragma unroll
        for (int p = 0; p < 2; ++p) {
            int L = tid + p * 256;
            int r = L >> 2, g = L & 3;
            const uint4 va = *reinterpret_cast<const uint4*>(
                &xb[(size_t)(row0 + r) * DDIM + d0 + g * 8]);
            *reinterpret_cast<uint4*>(&Ab[r * ASTR + g * 8]) = va;
            const uint4 vb = *reinterpret_cast<const uint4*>(
                &etb[(size_t)(c0 + r) * DDIM + d0 + g * 8]);
            *reinterpret_cast<uint4*>(&Bb[r * ASTR + g * 8]) = vb;
        }
        __syncthreads();
        bf16x8 bfr[4];
#pragma unroll
        for (int j = 0; j < 4; ++j)
            bfr[j] = *reinterpret_cast<const bf16x8*>(
                &Bb[(wc * 64 + j * 16 + l15) * ASTR + l4 * 8]);
#pragma unroll
        for (int i = 0; i < 4; ++i) {
            bf16x8 af = *reinterpret_cast<const bf16x8*>(
                &Ab[(wr * 64 + i * 16 + l15) * ASTR + l4 * 8]);
#pragma unroll
            for (int j = 0; j < 4; ++j)
                acc[i][j] = __builtin_amdgcn_mfma_f32_16x16x32_bf16(
                    af, bfr[j], acc[i][j], 0, 0, 0);
        }
        __syncthreads();
    }

    // screen-dist = e2[k] - 2*sim. C-layout: col=lane&15, row=(lane>>4)*4+reg.
    float rm[4][4];
#pragma unroll
    for (int i = 0; i < 4; ++i)
#pragma unroll
        for (int reg = 0; reg < 4; ++reg) {
            float m = INFINITY;
#pragma unroll
            for (int j = 0; j < 4; ++j) {
                float d = e2g[c0 + wc * 64 + j * 16 + l15] -
                          2.f * acc[i][j][reg];
                m = fminf(m, d);
            }
            rm[i][reg] = m;
        }
#pragma unroll
    for (int m = 1; m < 16; m <<= 1)
#pragma unroll
        for (int i = 0; i < 4; ++i)
#pragma unroll
            for (int reg = 0; reg < 4; ++reg)
                rm[i][reg] = fminf(rm[i][reg], __shfl_xor(rm[i][reg], m));
    if (l15 == 0) {
#pragma unroll
        for (int i = 0; i < 4; ++i)
#pragma unroll
            for (int reg = 0; reg < 4; ++reg)
                rowmin2[wc][wr * 64 + i * 16 + l4 * 4 + reg] = rm[i][reg];
    }
    __syncthreads();

    // per-(row, ks-block) screen min -> bmin (pick + rescan pruning key)
    if (tid < 128)
        bmin[(size_t)(row0 + tid) * 8 + ks] =
            fminf(rowmin2[0][tid], rowmin2[1][tid]);

#pragma unroll
    for (int i = 0; i < 4; ++i)
#pragma unroll
        for (int reg = 0; reg < 4; ++reg) {
            int rl = wr * 64 + i * 16 + l4 * 4 + reg;
            float thr = fminf(rowmin2[0][rl], rowmin2[1][rl]) +
                        screen_margin(x2g[row0 + rl]);
#pragma unroll
            for (int j = 0; j < 4; ++j) {
                int cl = wc * 64 + j * 16 + l15;
                float d = e2g[c0 + cl] - 2.f * acc[i][j][reg];
                if (d <= thr)
                    atomicOr(&mlds[rl][cl >> 5], 1u << (cl & 31));
            }
        }
    __syncthreads();
    for (int q = tid; q < 512; q += 256) {
        int r = q >> 2, wq = q & 3;
        masks[(size_t)(row0 + r) * 32 + ks * 4 + wq] = mlds[r][wq];
    }
}

// ---- pick (dense): prune blocks, popcount; 1 survivor => resolved ----------
__global__ __launch_bounds__(256) void vq_pick(
    const unsigned int* __restrict__ masks, const float* __restrict__ bmin,
    const float* __restrict__ x2g, int* __restrict__ idx,
    int* __restrict__ flag) {
    int row = blockIdx.x * 256 + threadIdx.x;  // 128 blocks
    float bm[8];
    float gmin = INFINITY;
#pragma unroll
    for (int s = 0; s < 8; ++s) {
        bm[s] = bmin[(size_t)row * 8 + s];
        gmin = fminf(gmin, bm[s]);
    }
    const float thr = gmin + screen_margin(x2g[row]);
    int total = 0;
    int saveq = 0;
    uint4 savev = make_uint4(0, 0, 0, 0);
#pragma unroll
    for (int q = 0; q < 8; ++q) {  // one uint4 == one 128-code block's bits
        if (bm[q] <= thr) {
            uint4 v = *reinterpret_cast<const uint4*>(
                &masks[(size_t)row * 32 + q * 4]);
            int c = __popc(v.x) + __popc(v.y) + __popc(v.z) + __popc(v.w);
            if (c) {
                saveq = q;
                savev = v;
            }
            total += c;
        }
    }
    if (total == 1) {
        // k*'s bit provably survives; a sole survivor must be k*
        int base = saveq * 128;
        int k = savev.x   ? base + __ffs(savev.x) - 1
                : savev.y ? base + 32 + __ffs(savev.y) - 1
                : savev.z ? base + 64 + __ffs(savev.z) - 1
                          : base + 96 + __ffs(savev.w) - 1;
        idx[row] = k & (KCODES - 1);
        flag[row] = 0;
    } else {
        flag[row] = 1;
    }
}

// ---- rescan (flag-gated): prune + parallel extract + np-exact dots ---------
__global__ __launch_bounds__(64) void vq_rescan(
    const float* __restrict__ x, const float* __restrict__ et,
    const float* __restrict__ x2g, const float* __restrict__ e2g,
    const unsigned int* __restrict__ masks, const float* __restrict__ bmin,
    const int* __restrict__ flag, int* __restrict__ idx) {
    const int lane = threadIdx.x;
    const int row = blockIdx.x;
    if (flag[row] == 0) return;

    __shared__ float xrow[256];
    __shared__ int cand[64];
    __shared__ float bmins[8];

    if (lane < 8) bmins[lane] = bmin[(size_t)row * 8 + lane];
    __syncthreads();
    float gmin = fminf(fminf(fminf(bmins[0], bmins[1]), fminf(bmins[2], bmins[3])),
                       fminf(fminf(bmins[4], bmins[5]), fminf(bmins[6], bmins[7])));
    const float x2r = x2g[row];
    const float margin = screen_margin(x2r);

    unsigned int wmask = 0u;
    if (lane < 32) {
        if (bmins[lane >> 2] <= gmin + margin)
            wmask = masks[(size_t)row * 32 + lane];
    }
    int mycnt = __popc(wmask);
    int pre = mycnt;
#pragma unroll
    for (int off = 1; off < 32; off <<= 1) {
        int t = __shfl_up(pre, off);
        if (lane >= off) pre += t;
    }
    const int total = __shfl(pre, 31);
    if (lane < 32) {
        int off = pre - mycnt;  // exclusive prefix (ascending k preserved)
        unsigned int b = wmask;
        while (b) {
            int t = __ffs(b) - 1;
            if (off < 64) cand[off] = lane * 32 + t;
            ++off;
            b &= b - 1;
        }
    }
    __syncthreads();

    if (total == 1) {
        if (lane == 0) idx[row] = cand[0] & (KCODES - 1);
    } else {
        *reinterpret_cast<float4*>(&xrow[lane * 4]) =
            *reinterpret_cast<const float4*>(&x[(size_t)row * DDIM + lane * 4]);
        __syncthreads();

        float best = INFINITY;
        int bk = 0x7fffffff;
        if (total <= 64) {
            if (lane < total) {
                int k = cand[lane];
                const float4* er =
                    reinterpret_cast<const float4*>(&et[(size_t)k * DDIM]);
                const float4* xr4 = reinterpret_cast<const float4*>(xrow);
                float s = 0.f;
#pragma unroll 4
                for (int g = 0; g < 64; ++g) {  // in-order d chain (np-exact)
                    float4 ev = er[g];
                    float4 xv = xr4[g];
                    s = fmaf(xv.x, ev.x, s);
                    s = fmaf(xv.y, ev.y, s);
                    s = fmaf(xv.z, ev.z, s);
                    s = fmaf(xv.w, ev.w, s);
                }
                float u = __fadd_rn(x2r, e2g[k]);
                best = __fsub_rn(u, __fmul_rn(2.0f, s));
                bk = k;
            }
        } else {
            // cold path (margin overflow — never expected): exact full rescan
#pragma unroll 1
            for (int c = 0; c < 16; ++c) {
                int k = lane + c * 64;
                const float4* er =
                    reinterpret_cast<const float4*>(&et[(size_t)k * DDIM]);
                const float4* xr4 = reinterpret_cast<const float4*>(xrow);
                float s = 0.f;
#pragma unroll 4
                for (int g = 0; g < 64; ++g) {
                    float4 ev = er[g];
                    float4 xv = xr4[g];
                    s = fmaf(xv.x, ev.x, s);
                    s = fmaf(xv.y, ev.y, s);
                    s = fmaf(xv.z, ev.z, s);
                    s = fmaf(xv.w, ev.w, s);
                }
                float u = __fadd_rn(x2r, e2g[k]);
                float dct = __fsub_rn(u, __fmul_rn(2.0f, s));
                if (dct < best || (dct == best && k < bk)) {
                    best = dct;
                    bk = k;
                }
            }
        }
#pragma unroll
        for (int m = 1; m < 64; m <<= 1) {
            float od = __shfl_xor(best, m);
            int oi = __shfl_xor(bk, m);
            if (od < best || (od == best && oi < bk)) {
                best = od;
                bk = oi;
            }
        }
        if (lane == 0) idx[row] = bk & (KCODES - 1);
    }
}

// ---- output: gather + fp32 STE out + loss partial (verified) ---------------
__global__ __launch_bounds__(256) void vq_output(
    const float* __restrict__ x, const float* __restrict__ et,
    const int* __restrict__ idx, float* __restrict__ out,
    float* __restrict__ blockloss) {
    __shared__ int skb[64];
    __shared__ float red[256];
    const int rb = blockIdx.x;
    const int tid = threadIdx.x;
    if (tid < 64) skb[tid] = idx[rb * 64 + tid];
    __syncthreads();
    float lsum = 0.f;
    for (int r = 0; r < 64; ++r) {
        int row = rb * 64 + r;
        int k = skb[r];
        float xv = x[(size_t)row * DDIM + tid];
        float qv = et[(size_t)k * DDIM + tid];
        float diff = __fsub_rn(qv, xv);
        float qst = __fadd_rn(xv, diff);
        out[(size_t)row * DDIM + tid] = qst;
        lsum = fmaf(diff, diff, lsum);
    }
    red[tid] = lsum;
    __syncthreads();
    for (int s = 128; s > 0; s >>= 1) {
        if (tid < s) red[tid] += red[tid + s];
        __syncthreads();
    }
    if (tid == 0) blockloss[rb] = red[0];
}

// ---- deterministic loss reduce (verified) ----------------------------------
__global__ __launch_bounds__(512) void vq_loss_reduce(
    const float* __restrict__ blockloss, float* __restrict__ out_loss) {
    __shared__ float red[512];
    int tid = threadIdx.x;
    red[tid] = blockloss[tid];
    __syncthreads();
    for (int s = 256; s > 0; s >>= 1) {
        if (tid < s) red[tid] += red[tid + s];
        __syncthreads();
    }
    if (tid == 0) {
        float m = __fmul_rn(red[0], 1.0f / (float)((size_t)NROWS * DDIM));
        out_loss[0] = __fadd_rn(__fmul_rn(0.25f, m), m);
    }
}

extern "C" void kernel_launch(void* const* d_in, const int* in_sizes, int n_in,
                              void* d_out, int out_size, void* d_ws,
                              size_t ws_size, hipStream_t stream) {
    const float* x = (const float*)d_in[0];  // [32768, 256] fp32
    const float* e = (const float*)d_in[1];  // [256, 1024]  fp32
    float* out = (float*)d_out;              // 8388608 qst + 1 loss, fp32

    float* ws = (float*)d_ws;
    float* x2 = ws;                                    // 32768
    float* e2 = x2 + NROWS;                            // 1024
    float* et = e2 + KCODES;                           // 262144
    unsigned short* etb = (unsigned short*)(et + (size_t)KCODES * DDIM);
    unsigned short* xb = etb + (size_t)KCODES * DDIM;  // 8388608 u16
    unsigned int* masks = (unsigned int*)(xb + (size_t)NROWS * DDIM);
    float* bmin = (float*)(masks + (size_t)NROWS * 32);  // 32768*8
    int* idx = (int*)(bmin + (size_t)NROWS * 8);       // 32768
    int* flag = idx + NROWS;                           // 32768
    float* blockloss = (float*)(flag + NROWS);         // 512

    vq_x2xb<<<NROWS / X2ROWS, 256, 0, stream>>>(x, x2, xb);
    vq_e2<<<KCODES / 256, 256, 0, stream>>>(e, e2);
    vq_transpose<<<dim3(32, 8), 256, 0, stream>>>(e, et, etb);
    vq_screen<<<dim3(NROWS / 128, KCODES / 128), 256, 0, stream>>>(
        xb, etb, e2, x2, masks, bmin);
    vq_pick<<<NROWS / 256, 256, 0, stream>>>(masks, bmin, x2, idx, flag);
    vq_rescan<<<NROWS, 64, 0, stream>>>(x, et, x2, e2, masks, bmin, flag, idx);
    vq_output<<<NROWS / 64, 256, 0, stream>>>(x, et, idx, out, blockloss);
    vq_loss_reduce<<<1, 512, 0, stream>>>(blockloss, out + (size_t)NROWS * DDIM);
}

// Round 15
// 128.760 us; speedup vs baseline: 1.3187x; 1.0903x over previous
//
#include <hip/hip_runtime.h>
#include <math.h>

#define NROWS 32768
#define DDIM 256
#define KCODES 1024

typedef __attribute__((ext_vector_type(8))) short bf16x8;
typedef __attribute__((ext_vector_type(4))) float f32x4;
typedef __attribute__((ext_vector_type(4))) unsigned short u16x4;
typedef __attribute__((address_space(3))) unsigned int lds_uint;
typedef const __attribute__((address_space(1))) unsigned int glb_uint;

__device__ __forceinline__ unsigned short f2bf(float f) {
    unsigned int u;
    __builtin_memcpy(&u, &f, 4);
    u += 0x7fffu + ((u >> 16) & 1u);
    return (unsigned short)(u >> 16);
}

// margin >= 2*eps_screen. Rigorous: 2eps <= 2^-7 * ||e||max * sqrt(x2),
// ||e|| <= 0.8  ->  0.00625*sqrt(x2). We use 2.24x that. (field-tested R13/14)
__device__ __forceinline__ float screen_margin(float x2v) {
    return 0.014f * sqrtf(x2v) + 5e-4f;
}

// ---- x2 = np.sum(x*x,1) via numpy AVX512 pairwise tree (bit-exact, R6) -----
constexpr int X2ROWS = 32;
__global__ __launch_bounds__(256) void vq_x2xb(const float* __restrict__ x,
                                               float* __restrict__ x2,
                                               unsigned short* __restrict__ xb) {
    __shared__ float lds[X2ROWS][257];
    const int rb = blockIdx.x;
    const int tid = threadIdx.x;
    const float4* src =
        reinterpret_cast<const float4*>(x + (size_t)rb * X2ROWS * DDIM);
#pragma unroll
    for (int i = 0; i < 8; ++i) {
        int e4 = tid + i * 256;
        int row = e4 >> 6;
        int col = e4 & 63;
        float4 v = src[e4];
        lds[row][col * 4 + 0] = v.x;
        lds[row][col * 4 + 1] = v.y;
        lds[row][col * 4 + 2] = v.z;
        lds[row][col * 4 + 3] = v.w;
        u16x4 h;
        h.x = f2bf(v.x);
        h.y = f2bf(v.y);
        h.z = f2bf(v.z);
        h.w = f2bf(v.w);
        *reinterpret_cast<u16x4*>(&xb[(size_t)rb * X2ROWS * DDIM + e4 * 4]) = h;
    }
    __syncthreads();
    if (tid < X2ROWS) {
        const float* r = lds[tid];
        float halves[2];
#pragma unroll
        for (int h = 0; h < 2; ++h) {
            const float* b = r + h * 128;
            float L[16];
#pragma unroll
            for (int p = 0; p < 16; ++p) {
                float t0 = __fmul_rn(b[p], b[p]);
                float t1 = __fmul_rn(b[16 + p], b[16 + p]);
                float t2 = __fmul_rn(b[32 + p], b[32 + p]);
                float t3 = __fmul_rn(b[48 + p], b[48 + p]);
                float t4 = __fmul_rn(b[64 + p], b[64 + p]);
                float t5 = __fmul_rn(b[80 + p], b[80 + p]);
                float t6 = __fmul_rn(b[96 + p], b[96 + p]);
                float t7 = __fmul_rn(b[112 + p], b[112 + p]);
                L[p] = __fadd_rn(
                    __fadd_rn(__fadd_rn(t0, t1), __fadd_rn(t2, t3)),
                    __fadd_rn(__fadd_rn(t4, t5), __fadd_rn(t6, t7)));
            }
            float s1[8];
#pragma unroll
            for (int p = 0; p < 8; ++p) s1[p] = __fadd_rn(L[p], L[p + 8]);
            float s2[4];
#pragma unroll
            for (int p = 0; p < 4; ++p) s2[p] = __fadd_rn(s1[p], s1[p + 4]);
            float s30 = __fadd_rn(s2[0], s2[2]);
            float s31 = __fadd_rn(s2[1], s2[3]);
            halves[h] = __fadd_rn(s30, s31);
        }
        x2[(size_t)rb * X2ROWS + tid] = __fadd_rn(halves[0], halves[1]);
    }
}

// ---- e2[k]: sequential axis-0 sum (bit-exact, R6) --------------------------
__global__ __launch_bounds__(256) void vq_e2(const float* __restrict__ e,
                                             float* __restrict__ e2) {
    int k = blockIdx.x * 256 + threadIdx.x;
    float v0 = e[k];
    float s = __fmul_rn(v0, v0);
    for (int d = 1; d < DDIM; ++d) {
        float v = e[d * KCODES + k];
        s = __fadd_rn(s, __fmul_rn(v, v));
    }
    e2[k] = s;
}

// ---- transpose E -> ET f32 + ETb bf16 --------------------------------------
__global__ __launch_bounds__(256) void vq_transpose(
    const float* __restrict__ e, float* __restrict__ et,
    unsigned short* __restrict__ etb) {
    __shared__ float tile[32][33];
    int bk = blockIdx.x;
    int bd = blockIdx.y;
    int tx = threadIdx.x & 31;
    int ty = threadIdx.x >> 5;
#pragma unroll
    for (int p = 0; p < 4; ++p)
        tile[ty + p * 8][tx] = e[(bd * 32 + ty + p * 8) * KCODES + bk * 32 + tx];
    __syncthreads();
#pragma unroll
    for (int p = 0; p < 4; ++p) {
        float v = tile[tx][ty + p * 8];
        size_t o = (size_t)(bk * 32 + ty + p * 8) * DDIM + bd * 32 + tx;
        et[o] = v;
        etb[o] = f2bf(v);
    }
}

// ---- screen: bf16 MFMA 128x128 + global_load_lds(16B) staging --------------
__global__ __launch_bounds__(256) void vq_screen(
    const unsigned short* __restrict__ xb, const unsigned short* __restrict__ etb,
    const float* __restrict__ e2g, const float* __restrict__ x2g,
    unsigned int* __restrict__ masks, float* __restrict__ bmin) {
    // linear tiles: [128 rows][32 d] bf16 = 8 KB each (no padding: required
    // by global_load_lds lane-order writes)
    __shared__ __align__(16) unsigned short Ab[128 * 32];
    __shared__ __align__(16) unsigned short Bb[128 * 32];
    __shared__ float rowmin2[2][128];
    __shared__ unsigned int mlds[128][4];

    const int rb = blockIdx.x;
    const int ks = blockIdx.y;
    const int row0 = rb * 128;
    const int c0 = ks * 128;
    const int tid = threadIdx.x;
    const int w = tid >> 6;
    const int lane = tid & 63;
    const int wr = w >> 1, wc = w & 1;
    const int l15 = lane & 15, l4 = lane >> 4;

    for (int q = tid; q < 512; q += 256)
        reinterpret_cast<unsigned int*>(mlds)[q] = 0u;

    f32x4 acc[4][4];
#pragma unroll
    for (int i = 0; i < 4; ++i)
#pragma unroll
        for (int j = 0; j < 4; ++j) acc[i][j] = (f32x4)(0.f);

    for (int d0 = 0; d0 < DDIM; d0 += 32) {
        // stage A and B via async global->LDS, 16 B per lane.
        // instruction covers elements idx = w*128 + p*64 + lane;
        // LDS dest = wave-uniform base + lane*16 (linear), so
        // r = idx>>2 (row), slot = idx&3 (16B slot = 8 bf16 within the row).
#pragma unroll
        for (int p = 0; p < 2; ++p) {
            int idx = w * 128 + p * 64 + lane;
            int r = idx >> 2, slot = idx & 3;
            const unsigned short* ga =
                &xb[(size_t)(row0 + r) * DDIM + d0 + slot * 8];
            __builtin_amdgcn_global_load_lds(
                (glb_uint*)ga, (lds_uint*)&Ab[(size_t)(w * 128 + p * 64) * 8],
                16, 0, 0);
            const unsigned short* gb =
                &etb[(size_t)(c0 + r) * DDIM + d0 + slot * 8];
            __builtin_amdgcn_global_load_lds(
                (glb_uint*)gb, (lds_uint*)&Bb[(size_t)(w * 128 + p * 64) * 8],
                16, 0, 0);
        }
        __syncthreads();
        bf16x8 bfr[4];
#pragma unroll
        for (int j = 0; j < 4; ++j)
            bfr[j] = *reinterpret_cast<const bf16x8*>(
                &Bb[(wc * 64 + j * 16 + l15) * 32 + l4 * 8]);
#pragma unroll
        for (int i = 0; i < 4; ++i) {
            bf16x8 af = *reinterpret_cast<const bf16x8*>(
                &Ab[(wr * 64 + i * 16 + l15) * 32 + l4 * 8]);
#pragma unroll
            for (int j = 0; j < 4; ++j)
                acc[i][j] = __builtin_amdgcn_mfma_f32_16x16x32_bf16(
                    af, bfr[j], acc[i][j], 0, 0, 0);
        }
        __syncthreads();
    }

    // screen-dist = e2[k] - 2*sim. C-layout: col=lane&15, row=(lane>>4)*4+reg.
    float rm[4][4];
#pragma unroll
    for (int i = 0; i < 4; ++i)
#pragma unroll
        for (int reg = 0; reg < 4; ++reg) {
            float m = INFINITY;
#pragma unroll
            for (int j = 0; j < 4; ++j) {
                float d = e2g[c0 + wc * 64 + j * 16 + l15] -
                          2.f * acc[i][j][reg];
                m = fminf(m, d);
            }
            rm[i][reg] = m;
        }
#pragma unroll
    for (int m = 1; m < 16; m <<= 1)
#pragma unroll
        for (int i = 0; i < 4; ++i)
#pragma unroll
            for (int reg = 0; reg < 4; ++reg)
                rm[i][reg] = fminf(rm[i][reg], __shfl_xor(rm[i][reg], m));
    if (l15 == 0) {
#pragma unroll
        for (int i = 0; i < 4; ++i)
#pragma unroll
            for (int reg = 0; reg < 4; ++reg)
                rowmin2[wc][wr * 64 + i * 16 + l4 * 4 + reg] = rm[i][reg];
    }
    __syncthreads();

    // per-(row, ks-block) screen min -> bmin (pick + rescan pruning key)
    if (tid < 128)
        bmin[(size_t)(row0 + tid) * 8 + ks] =
            fminf(rowmin2[0][tid], rowmin2[1][tid]);

#pragma unroll
    for (int i = 0; i < 4; ++i)
#pragma unroll
        for (int reg = 0; reg < 4; ++reg) {
            int rl = wr * 64 + i * 16 + l4 * 4 + reg;
            float thr = fminf(rowmin2[0][rl], rowmin2[1][rl]) +
                        screen_margin(x2g[row0 + rl]);
#pragma unroll
            for (int j = 0; j < 4; ++j) {
                int cl = wc * 64 + j * 16 + l15;
                float d = e2g[c0 + cl] - 2.f * acc[i][j][reg];
                if (d <= thr)
                    atomicOr(&mlds[rl][cl >> 5], 1u << (cl & 31));
            }
        }
    __syncthreads();
    for (int q = tid; q < 512; q += 256) {
        int r = q >> 2, wq = q & 3;
        masks[(size_t)(row0 + r) * 32 + ks * 4 + wq] = mlds[r][wq];
    }
}

// ---- pick (dense): prune blocks, popcount; 1 survivor => resolved ----------
__global__ __launch_bounds__(256) void vq_pick(
    const unsigned int* __restrict__ masks, const float* __restrict__ bmin,
    const float* __restrict__ x2g, int* __restrict__ idx,
    int* __restrict__ flag) {
    int row = blockIdx.x * 256 + threadIdx.x;  // 128 blocks
    float bm[8];
    float gmin = INFINITY;
#pragma unroll
    for (int s = 0; s < 8; ++s) {
        bm[s] = bmin[(size_t)row * 8 + s];
        gmin = fminf(gmin, bm[s]);
    }
    const float thr = gmin + screen_margin(x2g[row]);
    int total = 0;
    int saveq = 0;
    uint4 savev = make_uint4(0, 0, 0, 0);
#pragma unroll
    for (int q = 0; q < 8; ++q) {  // one uint4 == one 128-code block's bits
        if (bm[q] <= thr) {
            uint4 v = *reinterpret_cast<const uint4*>(
                &masks[(size_t)row * 32 + q * 4]);
            int c = __popc(v.x) + __popc(v.y) + __popc(v.z) + __popc(v.w);
            if (c) {
                saveq = q;
                savev = v;
            }
            total += c;
        }
    }
    if (total == 1) {
        // k*'s bit provably survives; a sole survivor must be k*
        int base = saveq * 128;
        int k = savev.x   ? base + __ffs(savev.x) - 1
                : savev.y ? base + 32 + __ffs(savev.y) - 1
                : savev.z ? base + 64 + __ffs(savev.z) - 1
                          : base + 96 + __ffs(savev.w) - 1;
        idx[row] = k & (KCODES - 1);
        flag[row] = 0;
    } else {
        flag[row] = 1;
    }
}

// ---- rescan (flag-gated): prune + parallel extract + np-exact dots ---------
__global__ __launch_bounds__(64) void vq_rescan(
    const float* __restrict__ x, const float* __restrict__ et,
    const float* __restrict__ x2g, const float* __restrict__ e2g,
    const unsigned int* __restrict__ masks, const float* __restrict__ bmin,
    const int* __restrict__ flag, int* __restrict__ idx) {
    const int lane = threadIdx.x;
    const int row = blockIdx.x;
    if (flag[row] == 0) return;

    __shared__ float xrow[256];
    __shared__ int cand[64];
    __shared__ float bmins[8];

    if (lane < 8) bmins[lane] = bmin[(size_t)row * 8 + lane];
    __syncthreads();
    float gmin = fminf(fminf(fminf(bmins[0], bmins[1]), fminf(bmins[2], bmins[3])),
                       fminf(fminf(bmins[4], bmins[5]), fminf(bmins[6], bmins[7])));
    const float x2r = x2g[row];
    const float margin = screen_margin(x2r);

    unsigned int wmask = 0u;
    if (lane < 32) {
        if (bmins[lane >> 2] <= gmin + margin)
            wmask = masks[(size_t)row * 32 + lane];
    }
    int mycnt = __popc(wmask);
    int pre = mycnt;
#pragma unroll
    for (int off = 1; off < 32; off <<= 1) {
        int t = __shfl_up(pre, off);
        if (lane >= off) pre += t;
    }
    const int total = __shfl(pre, 31);
    if (lane < 32) {
        int off = pre - mycnt;  // exclusive prefix (ascending k preserved)
        unsigned int b = wmask;
        while (b) {
            int t = __ffs(b) - 1;
            if (off < 64) cand[off] = lane * 32 + t;
            ++off;
            b &= b - 1;
        }
    }
    __syncthreads();

    if (total == 1) {
        if (lane == 0) idx[row] = cand[0] & (KCODES - 1);
    } else {
        *reinterpret_cast<float4*>(&xrow[lane * 4]) =
            *reinterpret_cast<const float4*>(&x[(size_t)row * DDIM + lane * 4]);
        __syncthreads();

        float best = INFINITY;
        int bk = 0x7fffffff;
        if (total <= 64) {
            if (lane < total) {
                int k = cand[lane];
                const float4* er =
                    reinterpret_cast<const float4*>(&et[(size_t)k * DDIM]);
                const float4* xr4 = reinterpret_cast<const float4*>(xrow);
                float s = 0.f;
#pragma unroll 4
                for (int g = 0; g < 64; ++g) {  // in-order d chain (np-exact)
                    float4 ev = er[g];
                    float4 xv = xr4[g];
                    s = fmaf(xv.x, ev.x, s);
                    s = fmaf(xv.y, ev.y, s);
                    s = fmaf(xv.z, ev.z, s);
                    s = fmaf(xv.w, ev.w, s);
                }
                float u = __fadd_rn(x2r, e2g[k]);
                best = __fsub_rn(u, __fmul_rn(2.0f, s));
                bk = k;
            }
        } else {
            // cold path (margin overflow — never expected): exact full rescan
#pragma unroll 1
            for (int c = 0; c < 16; ++c) {
                int k = lane + c * 64;
                const float4* er =
                    reinterpret_cast<const float4*>(&et[(size_t)k * DDIM]);
                const float4* xr4 = reinterpret_cast<const float4*>(xrow);
                float s = 0.f;
#pragma unroll 4
                for (int g = 0; g < 64; ++g) {
                    float4 ev = er[g];
                    float4 xv = xr4[g];
                    s = fmaf(xv.x, ev.x, s);
                    s = fmaf(xv.y, ev.y, s);
                    s = fmaf(xv.z, ev.z, s);
                    s = fmaf(xv.w, ev.w, s);
                }
                float u = __fadd_rn(x2r, e2g[k]);
                float dct = __fsub_rn(u, __fmul_rn(2.0f, s));
                if (dct < best || (dct == best && k < bk)) {
                    best = dct;
                    bk = k;
                }
            }
        }
#pragma unroll
        for (int m = 1; m < 64; m <<= 1) {
            float od = __shfl_xor(best, m);
            int oi = __shfl_xor(bk, m);
            if (od < best || (od == best && oi < bk)) {
                best = od;
                bk = oi;
            }
        }
        if (lane == 0) idx[row] = bk & (KCODES - 1);
    }
}

// ---- output: gather + fp32 STE out + loss partial (verified) ---------------
__global__ __launch_bounds__(256) void vq_output(
    const float* __restrict__ x, const float* __restrict__ et,
    const int* __restrict__ idx, float* __restrict__ out,
    float* __restrict__ blockloss) {
    __shared__ int skb[64];
    __shared__ float red[256];
    const int rb = blockIdx.x;
    const int tid = threadIdx.x;
    if (tid < 64) skb[tid] = idx[rb * 64 + tid];
    __syncthreads();
    float lsum = 0.f;
    for (int r = 0; r < 64; ++r) {
        int row = rb * 64 + r;
        int k = skb[r];
        float xv = x[(size_t)row * DDIM + tid];
        float qv = et[(size_t)k * DDIM + tid];
        float diff = __fsub_rn(qv, xv);
        float qst = __fadd_rn(xv, diff);
        out[(size_t)row * DDIM + tid] = qst;
        lsum = fmaf(diff, diff, lsum);
    }
    red[tid] = lsum;
    __syncthreads();
    for (int s = 128; s > 0; s >>= 1) {
        if (tid < s) red[tid] += red[tid + s];
        __syncthreads();
    }
    if (tid == 0) blockloss[rb] = red[0];
}

// ---- deterministic loss reduce (verified) ----------------------------------
__global__ __launch_bounds__(512) void vq_loss_reduce(
    const float* __restrict__ blockloss, float* __restrict__ out_loss) {
    __shared__ float red[512];
    int tid = threadIdx.x;
    red[tid] = blockloss[tid];
    __syncthreads();
    for (int s = 256; s > 0; s >>= 1) {
        if (tid < s) red[tid] += red[tid + s];
        __syncthreads();
    }
    if (tid == 0) {
        float m = __fmul_rn(red[0], 1.0f / (float)((size_t)NROWS * DDIM));
        out_loss[0] = __fadd_rn(__fmul_rn(0.25f, m), m);
    }
}

extern "C" void kernel_launch(void* const* d_in, const int* in_sizes, int n_in,
                              void* d_out, int out_size, void* d_ws,
                              size_t ws_size, hipStream_t stream) {
    const float* x = (const float*)d_in[0];  // [32768, 256] fp32
    const float* e = (const float*)d_in[1];  // [256, 1024]  fp32
    float* out = (float*)d_out;              // 8388608 qst + 1 loss, fp32

    float* ws = (float*)d_ws;
    float* x2 = ws;                                    // 32768
    float* e2 = x2 + NROWS;                            // 1024
    float* et = e2 + KCODES;                           // 262144
    unsigned short* etb = (unsigned short*)(et + (size_t)KCODES * DDIM);
    unsigned short* xb = etb + (size_t)KCODES * DDIM;  // 8388608 u16
    unsigned int* masks = (unsigned int*)(xb + (size_t)NROWS * DDIM);
    float* bmin = (float*)(masks + (size_t)NROWS * 32);  // 32768*8
    int* idx = (int*)(bmin + (size_t)NROWS * 8);       // 32768
    int* flag = idx + NROWS;                           // 32768
    float* blockloss = (float*)(flag + NROWS);         // 512

    vq_x2xb<<<NROWS / X2ROWS, 256, 0, stream>>>(x, x2, xb);
    vq_e2<<<KCODES / 256, 256, 0, stream>>>(e, e2);
    vq_transpose<<<dim3(32, 8), 256, 0, stream>>>(e, et, etb);
    vq_screen<<<dim3(NROWS / 128, KCODES / 128), 256, 0, stream>>>(
        xb, etb, e2, x2, masks, bmin);
    vq_pick<<<NROWS / 256, 256, 0, stream>>>(masks, bmin, x2, idx, flag);
    vq_rescan<<<NROWS, 64, 0, stream>>>(x, et, x2, e2, masks, bmin, flag, idx);
    vq_output<<<NROWS / 64, 256, 0, stream>>>(x, et, idx, out, blockloss);
    vq_loss_reduce<<<1, 512, 0, stream>>>(blockloss, out + (size_t)NROWS * DDIM);
}